// Round 1
// baseline (391.139 us; speedup 1.0000x reference)
//
#include <hip/hip_runtime.h>
#include <math.h>

// Layout facts (from reference): N=16384 rows, C=1000 cols, 7 heads.
// Row stride = 1000 floats = 4000 B -> every row base is 16B-aligned -> float4 ok.
// C/4 = 250 float4 per row; one 64-lane wave covers it in 4 vector loads/lane.

__global__ __launch_bounds__(256) void margin_kernel(
    const float* __restrict__ h0, const float* __restrict__ h1,
    const float* __restrict__ h2, const float* __restrict__ h3,
    const float* __restrict__ h4, const float* __restrict__ h5,
    const float* __restrict__ h6,
    const int* __restrict__ targets,
    float* __restrict__ margins,   // [7*N], margins[head*N + row]
    float* __restrict__ partials,  // [gridDim.x] block maxima (heads 0..5), -inf for mimic blocks
    int N, int C)
{
    const int lane = threadIdx.x & 63;
    const int waveInBlock = threadIdx.x >> 6;
    const int p = blockIdx.x * 4 + waveInBlock;   // (head,row) pair index
    const int head = p / N;                        // block-uniform: 4 | N
    const int row  = p - head * N;

    const float* base;
    switch (head) {
        case 0: base = h0; break;
        case 1: base = h1; break;
        case 2: base = h2; break;
        case 3: base = h3; break;
        case 4: base = h4; break;
        case 5: base = h5; break;
        default: base = h6; break;
    }
    base += (size_t)row * C;

    const float4* v = (const float4*)base;
    const int nvec = C >> 2;  // 250
    float m1 = -INFINITY, m2 = -INFINITY;
    #pragma unroll
    for (int it = 0; it < 4; ++it) {
        int idx = it * 64 + lane;
        if (idx < nvec) {
            float4 x = v[idx];
            float vals[4] = {x.x, x.y, x.z, x.w};
            #pragma unroll
            for (int k = 0; k < 4; ++k) {
                float val = vals[k];
                if (val > m1) { m2 = m1; m1 = val; }
                else if (val > m2) { m2 = val; }
            }
        }
    }
    // 64-lane butterfly top-2 reduction
    #pragma unroll
    for (int off = 32; off >= 1; off >>= 1) {
        float o1 = __shfl_xor(m1, off);
        float o2 = __shfl_xor(m2, off);
        float hi = fmaxf(m1, o1);
        float lo = fminf(m1, o1);
        m2 = fmaxf(lo, fmaxf(m2, o2));
        m1 = hi;
    }

    __shared__ float smax[4];
    if (lane == 0) {
        int t = targets[row];
        float tval = base[t];
        float margin = (tval == m1) ? (m1 - m2) : 0.0f;
        margins[head * N + row] = margin;
        smax[waveInBlock] = (head < 6) ? m1 : -INFINITY;  // max_preds excludes mimic
    }
    __syncthreads();
    if (threadIdx.x == 0) {
        float bm = fmaxf(fmaxf(smax[0], smax[1]), fmaxf(smax[2], smax[3]));
        partials[blockIdx.x] = bm;
    }
}

__global__ __launch_bounds__(1024) void reduce_max_kernel(
    const float* __restrict__ partials, int n, float* __restrict__ out)
{
    float m = -INFINITY;
    for (int i = threadIdx.x; i < n; i += 1024) m = fmaxf(m, partials[i]);
    #pragma unroll
    for (int off = 32; off >= 1; off >>= 1) m = fmaxf(m, __shfl_xor(m, off));
    __shared__ float s[16];
    int lane = threadIdx.x & 63, w = threadIdx.x >> 6;
    if (lane == 0) s[w] = m;
    __syncthreads();
    if (threadIdx.x == 0) {
        float r = -INFINITY;
        #pragma unroll
        for (int i = 0; i < 16; ++i) r = fmaxf(r, s[i]);
        out[0] = r;
    }
}

__global__ __launch_bounds__(256) void softmax_kernel(
    const float* __restrict__ margins, float* __restrict__ out, int N)
{
    int row = blockIdx.x * blockDim.x + threadIdx.x;
    if (row >= N) return;
    float m[7];
    float mx = -INFINITY;
    #pragma unroll
    for (int j = 0; j < 7; ++j) { m[j] = margins[j * N + row]; mx = fmaxf(mx, m[j]); }
    float s = 0.0f;
    #pragma unroll
    for (int j = 0; j < 7; ++j) { m[j] = expf((m[j] - mx) * 0.5f); s += m[j]; }  // /TEMPERATURE=2
    float inv = 1.0f / s;
    #pragma unroll
    for (int j = 0; j < 7; ++j) out[row * 7 + j] = m[j] * inv;
}

extern "C" void kernel_launch(void* const* d_in, const int* in_sizes, int n_in,
                              void* d_out, int out_size, void* d_ws, size_t ws_size,
                              hipStream_t stream) {
    const float* h0 = (const float*)d_in[0];
    const float* h1 = (const float*)d_in[1];
    const float* h2 = (const float*)d_in[2];
    const float* h3 = (const float*)d_in[3];
    const float* h4 = (const float*)d_in[4];
    const float* h5 = (const float*)d_in[5];
    const float* h6 = (const float*)d_in[6];  // mimic
    const int* targets = (const int*)d_in[7];
    // d_in[8] = n_test (== N at setup; output shape fixed accordingly)

    const int N = in_sizes[7];          // 16384
    const int C = in_sizes[0] / N;      // 1000

    float* margins  = (float*)d_ws;           // 7*N floats
    float* partials = margins + 7 * N;        // nblocks floats
    const int pairs  = 7 * N;
    const int nblocks = pairs / 4;            // 4 waves (pairs) per block; 4 | N

    margin_kernel<<<nblocks, 256, 0, stream>>>(h0, h1, h2, h3, h4, h5, h6,
                                               targets, margins, partials, N, C);
    reduce_max_kernel<<<1, 1024, 0, stream>>>(partials, nblocks, (float*)d_out);
    softmax_kernel<<<(N + 255) / 256, 256, 0, stream>>>(margins, (float*)d_out + 1, N);
}